// Round 1
// baseline (790.768 us; speedup 1.0000x reference)
//
#include <hip/hip_runtime.h>

#define N_NODES 100000
#define E_EDGES 1600000

// ---------------- degree ----------------
__global__ void deg_kernel(const int* __restrict__ dst, float* __restrict__ deg, int E) {
    int e = blockIdx.x * blockDim.x + threadIdx.x;
    if (e < E) atomicAdd(&deg[dst[e]], 1.0f);
}

__global__ void dinv_kernel(const float* __restrict__ deg, float* __restrict__ dinv, int n) {
    int i = blockIdx.x * blockDim.x + threadIdx.x;
    if (i < n) dinv[i] = rsqrtf(deg[i] + 2.0f);  // improved self-loop weight 2.0; deg+2 > 0 always
}

// ---------------- dense linear: Y[n,FOUT] = X[n,64] @ W[64,FOUT] ----------------
template <int FOUT>
__global__ void linear_kernel(const float* __restrict__ X, const float* __restrict__ W,
                              float* __restrict__ Y, int n) {
    constexpr int RPB = 256 / FOUT;  // rows per block
    __shared__ float Ws[64 * FOUT];
    __shared__ float Xs[RPB][64];
    const int tid = threadIdx.x;
    for (int i = tid; i < 64 * FOUT; i += 256) Ws[i] = W[i];
    const int row0 = blockIdx.x * RPB;
    for (int i = tid; i < RPB * 64; i += 256) {
        int r = row0 + (i >> 6);
        Xs[i >> 6][i & 63] = (r < n) ? X[r * 64 + (i & 63)] : 0.0f;
    }
    __syncthreads();
    const int rl  = tid / FOUT;
    const int col = tid % FOUT;
    const int row = row0 + rl;
    if (row >= n) return;
    float acc = 0.0f;
#pragma unroll
    for (int k = 0; k < 64; ++k) acc += Xs[rl][k] * Ws[k * FOUT + col];
    Y[row * FOUT + col] = acc;
}

// ---------------- edge scatter: AGG[dst,f] += H[src,f] * dinv[src]*dinv[dst] ----------------
template <int F>
__global__ void scatter_kernel(const int* __restrict__ src, const int* __restrict__ dst,
                               const float* __restrict__ dinv, const float* __restrict__ H,
                               float* __restrict__ AGG, int E) {
    int gid = blockIdx.x * blockDim.x + threadIdx.x;  // E*F <= 102.4M < 2^31
    int e = gid / F;
    int f = gid % F;
    if (e >= E) return;
    int s = src[e];
    int d = dst[e];
    float norm = dinv[s] * dinv[d];
    atomicAdd(&AGG[d * F + f], H[s * F + f] * norm);
}

// ---------------- finalize: OUT = AGG + HLIN * (2*dinv^2) + bias, optional ReLU ----------------
template <int F, bool RELU>
__global__ void finalize_kernel(const float* __restrict__ AGG, const float* __restrict__ HLIN,
                                const float* __restrict__ dinv, const float* __restrict__ bias,
                                float* __restrict__ OUT, int n) {
    int gid = blockIdx.x * blockDim.x + threadIdx.x;
    if (gid >= n * F) return;
    int i = gid / F;
    int f = gid % F;
    float di = dinv[i];
    float v = AGG[gid] + HLIN[gid] * (2.0f * di * di) + bias[f];
    if (RELU) v = fmaxf(v, 0.0f);
    OUT[gid] = v;
}

extern "C" void kernel_launch(void* const* d_in, const int* in_sizes, int n_in,
                              void* d_out, int out_size, void* d_ws, size_t ws_size,
                              hipStream_t stream) {
    const float* x  = (const float*)d_in[0];   // [N,64]
    const int*   ei = (const int*)d_in[1];     // [2,E] row-major: src then dst
    const float* W1 = (const float*)d_in[2];   // [64,64]
    const float* b1 = (const float*)d_in[3];   // [64]
    const float* W2 = (const float*)d_in[4];   // [64,32]
    const float* b2 = (const float*)d_in[5];   // [32]

    const int* srcp = ei;
    const int* dstp = ei + E_EDGES;

    // tuple return order: (out [N,32], feature_map [N,64]) concatenated flat
    float* out = (float*)d_out;                   // N*32
    float* fm  = (float*)d_out + N_NODES * 32;    // N*64 (also h1 input to layer 2)

    float* ws    = (float*)d_ws;
    float* deg   = ws;                              // N
    float* dinv  = deg + N_NODES;                   // N
    float* h1lin = dinv + N_NODES;                  // N*64
    float* agg1  = h1lin + (size_t)N_NODES * 64;    // N*64
    float* h2lin = agg1 + (size_t)N_NODES * 64;     // N*32
    float* agg2  = h2lin + (size_t)N_NODES * 32;    // N*32

    hipMemsetAsync(deg, 0, N_NODES * sizeof(float), stream);
    hipMemsetAsync(agg1, 0, (size_t)N_NODES * 64 * sizeof(float), stream);
    hipMemsetAsync(agg2, 0, (size_t)N_NODES * 32 * sizeof(float), stream);

    // shared degree / dinv (same graph both layers)
    deg_kernel<<<(E_EDGES + 255) / 256, 256, 0, stream>>>(dstp, deg, E_EDGES);
    dinv_kernel<<<(N_NODES + 255) / 256, 256, 0, stream>>>(deg, dinv, N_NODES);

    // ---- layer 1 ----
    linear_kernel<64><<<(N_NODES + 3) / 4, 256, 0, stream>>>(x, W1, h1lin, N_NODES);
    {
        int total = E_EDGES * 64;
        scatter_kernel<64><<<(total + 255) / 256, 256, 0, stream>>>(srcp, dstp, dinv, h1lin, agg1, E_EDGES);
    }
    finalize_kernel<64, true><<<(N_NODES * 64 + 255) / 256, 256, 0, stream>>>(agg1, h1lin, dinv, b1, fm, N_NODES);

    // ---- layer 2 (input = fm = relu'd h1) ----
    linear_kernel<32><<<(N_NODES + 7) / 8, 256, 0, stream>>>(fm, W2, h2lin, N_NODES);
    {
        int total = E_EDGES * 32;
        scatter_kernel<32><<<(total + 255) / 256, 256, 0, stream>>>(srcp, dstp, dinv, h2lin, agg2, E_EDGES);
    }
    finalize_kernel<32, false><<<(N_NODES * 32 + 255) / 256, 256, 0, stream>>>(agg2, h2lin, dinv, b2, out, N_NODES);
}

// Round 2
// 478.681 us; speedup vs baseline: 1.6520x; 1.6520x over previous
//
#include <hip/hip_runtime.h>

#define N_NODES 100000
#define E_EDGES 1600000
#define SCAN_BLK 256
#define NB_SCAN ((N_NODES + SCAN_BLK - 1) / SCAN_BLK)   // 391

// ---------------- degree histogram (int) ----------------
__global__ void deg_kernel(const int* __restrict__ dst, int* __restrict__ deg, int E) {
    int e = blockIdx.x * blockDim.x + threadIdx.x;
    if (e < E) atomicAdd(&deg[dst[e]], 1);
}

__global__ void dinv_kernel(const int* __restrict__ deg, float* __restrict__ dinv, int n) {
    int i = blockIdx.x * blockDim.x + threadIdx.x;
    if (i < n) dinv[i] = rsqrtf((float)deg[i] + 2.0f);  // improved self-loop weight 2.0
}

// ---------------- 3-phase exclusive scan of deg -> rowptr ----------------
__global__ void scan1_kernel(const int* __restrict__ deg, int* __restrict__ rowptr,
                             int* __restrict__ blocksum, int n) {
    __shared__ int s[SCAN_BLK];
    int tid = threadIdx.x;
    int i = blockIdx.x * SCAN_BLK + tid;
    int v = (i < n) ? deg[i] : 0;
    s[tid] = v;
    __syncthreads();
    for (int off = 1; off < SCAN_BLK; off <<= 1) {
        int t = (tid >= off) ? s[tid - off] : 0;
        __syncthreads();
        s[tid] += t;
        __syncthreads();
    }
    if (i < n) rowptr[i] = s[tid] - v;  // exclusive
    if (tid == SCAN_BLK - 1) blocksum[blockIdx.x] = s[tid];
}

__global__ void scan2_kernel(int* __restrict__ blocksum, int nb) {
    __shared__ int s[512];
    int tid = threadIdx.x;
    int v = (tid < nb) ? blocksum[tid] : 0;
    s[tid] = v;
    __syncthreads();
    for (int off = 1; off < 512; off <<= 1) {
        int t = (tid >= off) ? s[tid - off] : 0;
        __syncthreads();
        s[tid] += t;
        __syncthreads();
    }
    if (tid < nb) blocksum[tid] = s[tid] - v;  // exclusive block offsets
}

__global__ void scan3_kernel(int* __restrict__ rowptr, const int* __restrict__ blocksum, int n) {
    int i = blockIdx.x * SCAN_BLK + threadIdx.x;
    if (i < n) rowptr[i] += blocksum[blockIdx.x];
}

// ---------------- CSR build: group edges by dst, precompute norm ----------------
__global__ void build_kernel(const int* __restrict__ src, const int* __restrict__ dst,
                             const int* __restrict__ rowptr, int* __restrict__ cnt,
                             const float* __restrict__ dinv,
                             int* __restrict__ csrc, float* __restrict__ cnorm, int E) {
    int e = blockIdx.x * blockDim.x + threadIdx.x;
    if (e >= E) return;
    int s = src[e];
    int d = dst[e];
    int pos = rowptr[d] + atomicAdd(&cnt[d], 1);
    csrc[pos] = s;
    cnorm[pos] = dinv[s] * dinv[d];
}

// ---------------- dense linear: Y[n,FOUT] = X[n,64] @ W[64,FOUT] ----------------
template <int FOUT>
__global__ void linear_kernel(const float* __restrict__ X, const float* __restrict__ W,
                              float* __restrict__ Y, int n) {
    constexpr int RPB = 256 / FOUT;  // rows per block
    __shared__ float Ws[64 * FOUT];
    __shared__ float Xs[RPB][64];
    const int tid = threadIdx.x;
    for (int i = tid; i < 64 * FOUT; i += 256) Ws[i] = W[i];
    const int row0 = blockIdx.x * RPB;
    for (int i = tid; i < RPB * 64; i += 256) {
        int r = row0 + (i >> 6);
        Xs[i >> 6][i & 63] = (r < n) ? X[r * 64 + (i & 63)] : 0.0f;
    }
    __syncthreads();
    const int rl  = tid / FOUT;
    const int col = tid % FOUT;
    const int row = row0 + rl;
    if (row >= n) return;
    float acc = 0.0f;
#pragma unroll
    for (int k = 0; k < 64; ++k) acc += Xs[rl][k] * Ws[k * FOUT + col];
    Y[row * FOUT + col] = acc;
}

// ---------------- fused gather + self-loop + bias (+ReLU) ----------------
// F lanes per node; F=64 -> 1 wave/node, F=32 -> half-wave/node.
template <int F, bool RELU>
__global__ void gather_kernel(const int* __restrict__ rowptr, const int* __restrict__ deg,
                              const int* __restrict__ csrc, const float* __restrict__ cnorm,
                              const float* __restrict__ H, const float* __restrict__ dinv,
                              const float* __restrict__ bias, float* __restrict__ OUT, int n) {
    constexpr int NPB = 256 / F;  // nodes per block
    int node = blockIdx.x * NPB + (threadIdx.x / F);
    int lane = threadIdx.x % F;
    if (node >= n) return;
    int start = rowptr[node];
    int cnt = deg[node];
    float acc = 0.0f;
    int j = 0;
    // unroll by 2 to expose independent loads
    for (; j + 1 < cnt; j += 2) {
        int s0 = csrc[start + j];
        int s1 = csrc[start + j + 1];
        float w0 = cnorm[start + j];
        float w1 = cnorm[start + j + 1];
        float v0 = H[(size_t)s0 * F + lane];
        float v1 = H[(size_t)s1 * F + lane];
        acc += v0 * w0 + v1 * w1;
    }
    if (j < cnt) {
        int s0 = csrc[start + j];
        acc += H[(size_t)s0 * F + lane] * cnorm[start + j];
    }
    float di = dinv[node];
    float v = acc + H[(size_t)node * F + lane] * (2.0f * di * di) + bias[lane];
    if (RELU) v = fmaxf(v, 0.0f);
    OUT[(size_t)node * F + lane] = v;
}

extern "C" void kernel_launch(void* const* d_in, const int* in_sizes, int n_in,
                              void* d_out, int out_size, void* d_ws, size_t ws_size,
                              hipStream_t stream) {
    const float* x  = (const float*)d_in[0];   // [N,64]
    const int*   ei = (const int*)d_in[1];     // [2,E] row-major: src then dst
    const float* W1 = (const float*)d_in[2];   // [64,64]
    const float* b1 = (const float*)d_in[3];   // [64]
    const float* W2 = (const float*)d_in[4];   // [64,32]
    const float* b2 = (const float*)d_in[5];   // [32]

    const int* srcp = ei;
    const int* dstp = ei + E_EDGES;

    // tuple return order: (out [N,32], feature_map [N,64]) concatenated flat
    float* out = (float*)d_out;                   // N*32
    float* fm  = (float*)d_out + N_NODES * 32;    // N*64 (also h1 input to layer 2)

    // workspace layout
    char* w = (char*)d_ws;
    int*   deg     = (int*)w;                 w += sizeof(int) * N_NODES;
    int*   rowptr  = (int*)w;                 w += sizeof(int) * N_NODES;
    int*   cnt     = (int*)w;                 w += sizeof(int) * N_NODES;
    int*   bsum    = (int*)w;                 w += sizeof(int) * 512;
    float* dinv    = (float*)w;               w += sizeof(float) * N_NODES;
    int*   csrc    = (int*)w;                 w += sizeof(int) * E_EDGES;
    float* cnorm   = (float*)w;               w += sizeof(float) * E_EDGES;
    float* h1lin   = (float*)w;               w += sizeof(float) * (size_t)N_NODES * 64;
    float* h2lin   = (float*)w;               w += sizeof(float) * (size_t)N_NODES * 32;

    hipMemsetAsync(deg, 0, sizeof(int) * N_NODES, stream);
    hipMemsetAsync(cnt, 0, sizeof(int) * N_NODES, stream);

    // ---- graph preprocessing (shared by both layers) ----
    deg_kernel<<<(E_EDGES + 255) / 256, 256, 0, stream>>>(dstp, deg, E_EDGES);
    dinv_kernel<<<(N_NODES + 255) / 256, 256, 0, stream>>>(deg, dinv, N_NODES);
    scan1_kernel<<<NB_SCAN, SCAN_BLK, 0, stream>>>(deg, rowptr, bsum, N_NODES);
    scan2_kernel<<<1, 512, 0, stream>>>(bsum, NB_SCAN);
    scan3_kernel<<<NB_SCAN, SCAN_BLK, 0, stream>>>(rowptr, bsum, N_NODES);
    build_kernel<<<(E_EDGES + 255) / 256, 256, 0, stream>>>(srcp, dstp, rowptr, cnt, dinv,
                                                            csrc, cnorm, E_EDGES);

    // ---- layer 1 ----
    linear_kernel<64><<<(N_NODES + 3) / 4, 256, 0, stream>>>(x, W1, h1lin, N_NODES);
    gather_kernel<64, true><<<(N_NODES + 3) / 4, 256, 0, stream>>>(
        rowptr, deg, csrc, cnorm, h1lin, dinv, b1, fm, N_NODES);

    // ---- layer 2 (input = fm = relu'd h1) ----
    linear_kernel<32><<<(N_NODES + 7) / 8, 256, 0, stream>>>(fm, W2, h2lin, N_NODES);
    gather_kernel<32, false><<<(N_NODES + 7) / 8, 256, 0, stream>>>(
        rowptr, deg, csrc, cnorm, h2lin, dinv, b2, out, N_NODES);
}

// Round 3
// 404.022 us; speedup vs baseline: 1.9572x; 1.1848x over previous
//
#include <hip/hip_runtime.h>

#define N_NODES 100000
#define E_EDGES 1600000
#define SCAN_BLK 256
#define NB_SCAN ((N_NODES + SCAN_BLK - 1) / SCAN_BLK)   // 391

// ---- bf16x2 pack/unpack (RNE) ----
__device__ inline unsigned pack_bf16x2(float a, float b) {
    union { float f; unsigned u; } ua, ub;
    ua.f = a; ub.f = b;
    unsigned ra = (ua.u + 0x7fffu + ((ua.u >> 16) & 1u)) >> 16;
    unsigned rb = (ub.u + 0x7fffu + ((ub.u >> 16) & 1u)) >> 16;
    return ra | (rb << 16);
}
__device__ inline float bf_lo(unsigned u) { union { unsigned u; float f; } t; t.u = u << 16; return t.f; }
__device__ inline float bf_hi(unsigned u) { union { unsigned u; float f; } t; t.u = u & 0xffff0000u; return t.f; }

// ---------------- degree histogram (int) ----------------
__global__ void deg_kernel(const int* __restrict__ dst, int* __restrict__ deg, int E) {
    int e = blockIdx.x * blockDim.x + threadIdx.x;
    if (e < E) atomicAdd(&deg[dst[e]], 1);
}

__global__ void dinv_kernel(const int* __restrict__ deg, float* __restrict__ dinv, int n) {
    int i = blockIdx.x * blockDim.x + threadIdx.x;
    if (i < n) dinv[i] = rsqrtf((float)deg[i] + 2.0f);  // improved self-loop weight 2.0
}

// ---------------- 3-phase exclusive scan of deg -> rowptr ----------------
__global__ void scan1_kernel(const int* __restrict__ deg, int* __restrict__ rowptr,
                             int* __restrict__ blocksum, int n) {
    __shared__ int s[SCAN_BLK];
    int tid = threadIdx.x;
    int i = blockIdx.x * SCAN_BLK + tid;
    int v = (i < n) ? deg[i] : 0;
    s[tid] = v;
    __syncthreads();
    for (int off = 1; off < SCAN_BLK; off <<= 1) {
        int t = (tid >= off) ? s[tid - off] : 0;
        __syncthreads();
        s[tid] += t;
        __syncthreads();
    }
    if (i < n) rowptr[i] = s[tid] - v;  // exclusive
    if (tid == SCAN_BLK - 1) blocksum[blockIdx.x] = s[tid];
}

__global__ void scan2_kernel(int* __restrict__ blocksum, int nb) {
    __shared__ int s[512];
    int tid = threadIdx.x;
    int v = (tid < nb) ? blocksum[tid] : 0;
    s[tid] = v;
    __syncthreads();
    for (int off = 1; off < 512; off <<= 1) {
        int t = (tid >= off) ? s[tid - off] : 0;
        __syncthreads();
        s[tid] += t;
        __syncthreads();
    }
    if (tid < nb) blocksum[tid] = s[tid] - v;  // exclusive block offsets
}

__global__ void scan3_kernel(int* __restrict__ rowptr, const int* __restrict__ blocksum, int n) {
    int i = blockIdx.x * SCAN_BLK + threadIdx.x;
    if (i < n) rowptr[i] += blocksum[blockIdx.x];
}

// ---------------- CSR build: group edge srcs by dst ----------------
__global__ void build_kernel(const int* __restrict__ src, const int* __restrict__ dst,
                             const int* __restrict__ rowptr, int* __restrict__ cnt,
                             int* __restrict__ csrc, int E) {
    int e = blockIdx.x * blockDim.x + threadIdx.x;
    if (e >= E) return;
    int s = src[e];
    int d = dst[e];
    int pos = rowptr[d] + atomicAdd(&cnt[d], 1);
    csrc[pos] = s;
}

// ---------------- dense linear + dinv-scale + bf16x2 pack ----------------
// HS[row][c] (uint) = bf16x2( (X@W)[row][2c]*dinv[row], (X@W)[row][2c+1]*dinv[row] )
template <int FOUT>
__global__ void linear_kernel(const float* __restrict__ X, const float* __restrict__ W,
                              const float* __restrict__ dinv, unsigned* __restrict__ HS, int n) {
    constexpr int CP = FOUT / 2;       // col pairs
    constexpr int RPB = 256 / CP;      // rows per block
    __shared__ float Ws[64 * FOUT];
    __shared__ float Xs[RPB][64];
    const int tid = threadIdx.x;
    for (int i = tid; i < 64 * FOUT; i += 256) Ws[i] = W[i];
    const int row0 = blockIdx.x * RPB;
    for (int i = tid; i < RPB * 64; i += 256) {
        int r = row0 + (i >> 6);
        Xs[i >> 6][i & 63] = (r < n) ? X[r * 64 + (i & 63)] : 0.0f;
    }
    __syncthreads();
    const int rl = tid / CP;
    const int c  = tid % CP;
    const int row = row0 + rl;
    if (row >= n) return;
    float acc0 = 0.0f, acc1 = 0.0f;
#pragma unroll
    for (int k = 0; k < 64; ++k) {
        float xv = Xs[rl][k];
        acc0 += xv * Ws[k * FOUT + 2 * c];
        acc1 += xv * Ws[k * FOUT + 2 * c + 1];
    }
    float d = dinv[row];
    HS[(size_t)row * CP + c] = pack_bf16x2(acc0 * d, acc1 * d);
}

// ---------------- fused gather + self-loop + bias (+ReLU) ----------------
// G = F/2 lanes per node; each lane owns 2 features (one bf16x2 per row read).
// out[node][f] = dinv[node]*( 2*hs[node][f] + sum_s hs[s][f] ) + bias[f]
template <int F, bool RELU>
__global__ void gather_kernel(const int* __restrict__ rowptr, const int* __restrict__ deg,
                              const int* __restrict__ csrc, const unsigned* __restrict__ HS,
                              const float* __restrict__ dinv, const float* __restrict__ bias,
                              float* __restrict__ OUT, int n) {
    constexpr int G = F / 2;
    constexpr int NPB = 256 / G;
    int node = blockIdx.x * NPB + (threadIdx.x / G);
    int l = threadIdx.x % G;
    if (node >= n) return;
    int start = rowptr[node];
    int cnt = deg[node];
    // self-loop: weight 2
    unsigned us = HS[(size_t)node * G + l];
    float a0 = 2.0f * bf_lo(us);
    float a1 = 2.0f * bf_hi(us);
    int j = start, end = start + cnt;
    for (; j + 3 < end; j += 4) {
        int s0 = csrc[j], s1 = csrc[j + 1], s2 = csrc[j + 2], s3 = csrc[j + 3];
        unsigned u0 = HS[(size_t)s0 * G + l];
        unsigned u1 = HS[(size_t)s1 * G + l];
        unsigned u2 = HS[(size_t)s2 * G + l];
        unsigned u3 = HS[(size_t)s3 * G + l];
        a0 += bf_lo(u0) + bf_lo(u1) + bf_lo(u2) + bf_lo(u3);
        a1 += bf_hi(u0) + bf_hi(u1) + bf_hi(u2) + bf_hi(u3);
    }
    for (; j < end; ++j) {
        unsigned u = HS[(size_t)csrc[j] * G + l];
        a0 += bf_lo(u);
        a1 += bf_hi(u);
    }
    float dd = dinv[node];
    float2 bb = ((const float2*)bias)[l];
    float o0 = a0 * dd + bb.x;
    float o1 = a1 * dd + bb.y;
    if (RELU) { o0 = fmaxf(o0, 0.0f); o1 = fmaxf(o1, 0.0f); }
    ((float2*)OUT)[(size_t)node * G + l] = make_float2(o0, o1);
}

extern "C" void kernel_launch(void* const* d_in, const int* in_sizes, int n_in,
                              void* d_out, int out_size, void* d_ws, size_t ws_size,
                              hipStream_t stream) {
    const float* x  = (const float*)d_in[0];   // [N,64]
    const int*   ei = (const int*)d_in[1];     // [2,E] row-major: src then dst
    const float* W1 = (const float*)d_in[2];   // [64,64]
    const float* b1 = (const float*)d_in[3];   // [64]
    const float* W2 = (const float*)d_in[4];   // [64,32]
    const float* b2 = (const float*)d_in[5];   // [32]

    const int* srcp = ei;
    const int* dstp = ei + E_EDGES;

    // tuple return order: (out [N,32], feature_map [N,64]) concatenated flat
    float* out = (float*)d_out;                   // N*32
    float* fm  = (float*)d_out + N_NODES * 32;    // N*64 (also h1 input to layer 2)

    // workspace layout
    char* w = (char*)d_ws;
    int*      deg    = (int*)w;       w += sizeof(int) * N_NODES;
    int*      rowptr = (int*)w;       w += sizeof(int) * N_NODES;
    int*      cnt    = (int*)w;       w += sizeof(int) * N_NODES;
    int*      bsum   = (int*)w;       w += sizeof(int) * 512;
    float*    dinv   = (float*)w;     w += sizeof(float) * N_NODES;
    int*      csrc   = (int*)w;       w += sizeof(int) * E_EDGES;
    unsigned* HS1    = (unsigned*)w;  w += sizeof(unsigned) * (size_t)N_NODES * 32;  // bf16x2 of h1*dinv
    unsigned* HS2    = (unsigned*)w;  w += sizeof(unsigned) * (size_t)N_NODES * 16;  // bf16x2 of h2*dinv

    hipMemsetAsync(deg, 0, sizeof(int) * N_NODES, stream);
    hipMemsetAsync(cnt, 0, sizeof(int) * N_NODES, stream);

    // ---- graph preprocessing (shared by both layers) ----
    deg_kernel<<<(E_EDGES + 255) / 256, 256, 0, stream>>>(dstp, deg, E_EDGES);
    dinv_kernel<<<(N_NODES + 255) / 256, 256, 0, stream>>>(deg, dinv, N_NODES);
    scan1_kernel<<<NB_SCAN, SCAN_BLK, 0, stream>>>(deg, rowptr, bsum, N_NODES);
    scan2_kernel<<<1, 512, 0, stream>>>(bsum, NB_SCAN);
    scan3_kernel<<<NB_SCAN, SCAN_BLK, 0, stream>>>(rowptr, bsum, N_NODES);
    build_kernel<<<(E_EDGES + 255) / 256, 256, 0, stream>>>(srcp, dstp, rowptr, cnt, csrc, E_EDGES);

    // ---- layer 1: HS1 = bf16((x@W1)*dinv); fm = relu(gather) ----
    linear_kernel<64><<<(N_NODES + 7) / 8, 256, 0, stream>>>(x, W1, dinv, HS1, N_NODES);
    gather_kernel<64, true><<<(N_NODES + 7) / 8, 256, 0, stream>>>(
        rowptr, deg, csrc, HS1, dinv, b1, fm, N_NODES);

    // ---- layer 2: HS2 = bf16((fm@W2)*dinv); out = gather ----
    linear_kernel<32><<<(N_NODES + 15) / 16, 256, 0, stream>>>(fm, W2, dinv, HS2, N_NODES);
    gather_kernel<32, false><<<(N_NODES + 15) / 16, 256, 0, stream>>>(
        rowptr, deg, csrc, HS2, dinv, b2, out, N_NODES);
}

// Round 4
// 333.360 us; speedup vs baseline: 2.3721x; 1.2120x over previous
//
#include <hip/hip_runtime.h>

#define N_NODES 100000
#define E_EDGES 1600000
#define SCAN_BLK 256
#define NB_SCAN ((N_NODES + SCAN_BLK - 1) / SCAN_BLK)   // 391

// bucketed CSR build
#define BSHIFT 7
#define BSIZE 128
#define NBUCK ((N_NODES + BSIZE - 1) / BSIZE)           // 782
#define STAGE_TPB 1024
#define STAGE_EPT 8
#define STAGE_CHUNK (STAGE_TPB * STAGE_EPT)             // 8192
#define BUCKET_CAP 4096                                  // >> max bucket edges (~2300)

// ---- bf16x2 pack/unpack (RNE) ----
__device__ inline unsigned pack_bf16x2(float a, float b) {
    union { float f; unsigned u; } ua, ub;
    ua.f = a; ub.f = b;
    unsigned ra = (ua.u + 0x7fffu + ((ua.u >> 16) & 1u)) >> 16;
    unsigned rb = (ub.u + 0x7fffu + ((ub.u >> 16) & 1u)) >> 16;
    return ra | (rb << 16);
}
__device__ inline float bf_lo(unsigned u) { union { unsigned u; float f; } t; t.u = u << 16; return t.f; }
__device__ inline float bf_hi(unsigned u) { union { unsigned u; float f; } t; t.u = u & 0xffff0000u; return t.f; }

// ---------------- degree histogram (int) ----------------
__global__ void deg_kernel(const int* __restrict__ dst, int* __restrict__ deg, int E) {
    int e = blockIdx.x * blockDim.x + threadIdx.x;
    if (e < E) atomicAdd(&deg[dst[e]], 1);
}

__global__ void dinv_kernel(const int* __restrict__ deg, float* __restrict__ dinv, int n) {
    int i = blockIdx.x * blockDim.x + threadIdx.x;
    if (i < n) dinv[i] = rsqrtf((float)deg[i] + 2.0f);  // improved self-loop weight 2.0
}

// ---------------- 3-phase exclusive scan of deg -> rowptr ----------------
__global__ void scan1_kernel(const int* __restrict__ deg, int* __restrict__ rowptr,
                             int* __restrict__ blocksum, int n) {
    __shared__ int s[SCAN_BLK];
    int tid = threadIdx.x;
    int i = blockIdx.x * SCAN_BLK + tid;
    int v = (i < n) ? deg[i] : 0;
    s[tid] = v;
    __syncthreads();
    for (int off = 1; off < SCAN_BLK; off <<= 1) {
        int t = (tid >= off) ? s[tid - off] : 0;
        __syncthreads();
        s[tid] += t;
        __syncthreads();
    }
    if (i < n) rowptr[i] = s[tid] - v;  // exclusive
    if (tid == SCAN_BLK - 1) blocksum[blockIdx.x] = s[tid];
}

__global__ void scan2_kernel(int* __restrict__ blocksum, int nb) {
    __shared__ int s[512];
    int tid = threadIdx.x;
    int v = (tid < nb) ? blocksum[tid] : 0;
    s[tid] = v;
    __syncthreads();
    for (int off = 1; off < 512; off <<= 1) {
        int t = (tid >= off) ? s[tid - off] : 0;
        __syncthreads();
        s[tid] += t;
        __syncthreads();
    }
    if (tid < nb) blocksum[tid] = s[tid] - v;  // exclusive block offsets
}

__global__ void scan3_kernel(int* __restrict__ rowptr, const int* __restrict__ blocksum, int n) {
    int i = blockIdx.x * SCAN_BLK + threadIdx.x;
    if (i < n) rowptr[i] += blocksum[blockIdx.x];
}

// ---------------- bucket cursor init: gcursor[b] = rowptr[b*BSIZE] ----------------
__global__ void cursor_init_kernel(const int* __restrict__ rowptr, int* __restrict__ gcursor) {
    int b = blockIdx.x * blockDim.x + threadIdx.x;
    if (b < NBUCK) gcursor[b] = rowptr[b * BSIZE];
}

// ---------------- pass B: stage edges into bucket-major order ----------------
// record = src | ((dst & 127) << 17); src < 2^17
__global__ void __launch_bounds__(STAGE_TPB) stage_kernel(
    const int* __restrict__ src, const int* __restrict__ dst,
    int* __restrict__ gcursor, unsigned* __restrict__ staged, int E) {
    __shared__ int hist[NBUCK];
    __shared__ int base[NBUCK];
    __shared__ int cnt2[NBUCK];
    const int tid = threadIdx.x;
    const int e0 = blockIdx.x * STAGE_CHUNK;
    for (int i = tid; i < NBUCK; i += STAGE_TPB) { hist[i] = 0; cnt2[i] = 0; }
    __syncthreads();
    int d[STAGE_EPT], s[STAGE_EPT];
#pragma unroll
    for (int k = 0; k < STAGE_EPT; ++k) {
        int e = e0 + k * STAGE_TPB + tid;
        if (e < E) {
            d[k] = dst[e];
            s[k] = src[e];
            atomicAdd(&hist[d[k] >> BSHIFT], 1);
        } else {
            d[k] = -1;
        }
    }
    __syncthreads();
    for (int i = tid; i < NBUCK; i += STAGE_TPB)
        if (hist[i] > 0) base[i] = atomicAdd(&gcursor[i], hist[i]);
    __syncthreads();
#pragma unroll
    for (int k = 0; k < STAGE_EPT; ++k) {
        if (d[k] >= 0) {
            int b = d[k] >> BSHIFT;
            int pos = base[b] + atomicAdd(&cnt2[b], 1);
            staged[pos] = (unsigned)s[k] | ((unsigned)(d[k] & (BSIZE - 1)) << 17);
        }
    }
}

// ---------------- pass C: per-bucket fine CSR (coalesced writes) ----------------
__global__ void bucket_csr_kernel(const unsigned* __restrict__ staged,
                                  const int* __restrict__ rowptr,
                                  const int* __restrict__ deg,
                                  int* __restrict__ csrc, int n, int E) {
    __shared__ int lrp[BSIZE];   // per-node local exclusive offsets
    __shared__ int lcnt[BSIZE];
    __shared__ int lsrc[BUCKET_CAP];
    const int b = blockIdx.x;
    const int node0 = b * BSIZE;
    const int nn = min(BSIZE, n - node0);
    const int tid = threadIdx.x;  // 256
    int mydeg = 0;
    if (tid < BSIZE) {
        mydeg = (tid < nn) ? deg[node0 + tid] : 0;
        lrp[tid] = mydeg;
        lcnt[tid] = 0;
    }
    __syncthreads();
    // inclusive scan over lrp[0..BSIZE)
    for (int off = 1; off < BSIZE; off <<= 1) {
        int v = 0;
        if (tid < BSIZE && tid >= off) v = lrp[tid - off];
        __syncthreads();
        if (tid < BSIZE) lrp[tid] += v;
        __syncthreads();
    }
    int inc = (tid < BSIZE) ? lrp[tid] : 0;
    __syncthreads();
    if (tid < BSIZE) lrp[tid] = inc - mydeg;  // exclusive
    __syncthreads();
    const int ebase = rowptr[node0];
    const int eend = (node0 + BSIZE < n) ? rowptr[node0 + BSIZE] : E;
    const int ecnt = eend - ebase;
    for (int i = tid; i < ecnt; i += 256) {
        unsigned r = staged[ebase + i];
        int dl = (int)(r >> 17);
        int sv = (int)(r & 0x1FFFFu);
        int pos = lrp[dl] + atomicAdd(&lcnt[dl], 1);
        if (pos < BUCKET_CAP) lsrc[pos] = sv;
    }
    __syncthreads();
    for (int i = tid; i < ecnt; i += 256)
        csrc[ebase + i] = lsrc[i];
}

// ---------------- dense linear + dinv-scale + bf16x2 pack ----------------
template <int FOUT>
__global__ void linear_kernel(const float* __restrict__ X, const float* __restrict__ W,
                              const float* __restrict__ dinv, unsigned* __restrict__ HS, int n) {
    constexpr int CP = FOUT / 2;       // col pairs
    constexpr int RPB = 256 / CP;      // rows per block
    __shared__ float Ws[64 * FOUT];
    __shared__ float Xs[RPB][64];
    const int tid = threadIdx.x;
    for (int i = tid; i < 64 * FOUT; i += 256) Ws[i] = W[i];
    const int row0 = blockIdx.x * RPB;
    for (int i = tid; i < RPB * 64; i += 256) {
        int r = row0 + (i >> 6);
        Xs[i >> 6][i & 63] = (r < n) ? X[r * 64 + (i & 63)] : 0.0f;
    }
    __syncthreads();
    const int rl = tid / CP;
    const int c  = tid % CP;
    const int row = row0 + rl;
    if (row >= n) return;
    float acc0 = 0.0f, acc1 = 0.0f;
#pragma unroll
    for (int k = 0; k < 64; ++k) {
        float xv = Xs[rl][k];
        acc0 += xv * Ws[k * FOUT + 2 * c];
        acc1 += xv * Ws[k * FOUT + 2 * c + 1];
    }
    float d = dinv[row];
    HS[(size_t)row * CP + c] = pack_bf16x2(acc0 * d, acc1 * d);
}

// ---------------- fused gather + self-loop + bias (+ReLU) ----------------
template <int F, bool RELU>
__global__ void gather_kernel(const int* __restrict__ rowptr, const int* __restrict__ deg,
                              const int* __restrict__ csrc, const unsigned* __restrict__ HS,
                              const float* __restrict__ dinv, const float* __restrict__ bias,
                              float* __restrict__ OUT, int n) {
    constexpr int G = F / 2;
    constexpr int NPB = 256 / G;
    int node = blockIdx.x * NPB + (threadIdx.x / G);
    int l = threadIdx.x % G;
    if (node >= n) return;
    int start = rowptr[node];
    int cnt = deg[node];
    unsigned us = HS[(size_t)node * G + l];
    float a0 = 2.0f * bf_lo(us);
    float a1 = 2.0f * bf_hi(us);
    int j = start, end = start + cnt;
    for (; j + 3 < end; j += 4) {
        int s0 = csrc[j], s1 = csrc[j + 1], s2 = csrc[j + 2], s3 = csrc[j + 3];
        unsigned u0 = HS[(size_t)s0 * G + l];
        unsigned u1 = HS[(size_t)s1 * G + l];
        unsigned u2 = HS[(size_t)s2 * G + l];
        unsigned u3 = HS[(size_t)s3 * G + l];
        a0 += bf_lo(u0) + bf_lo(u1) + bf_lo(u2) + bf_lo(u3);
        a1 += bf_hi(u0) + bf_hi(u1) + bf_hi(u2) + bf_hi(u3);
    }
    for (; j < end; ++j) {
        unsigned u = HS[(size_t)csrc[j] * G + l];
        a0 += bf_lo(u);
        a1 += bf_hi(u);
    }
    float dd = dinv[node];
    float2 bb = ((const float2*)bias)[l];
    float o0 = a0 * dd + bb.x;
    float o1 = a1 * dd + bb.y;
    if (RELU) { o0 = fmaxf(o0, 0.0f); o1 = fmaxf(o1, 0.0f); }
    ((float2*)OUT)[(size_t)node * G + l] = make_float2(o0, o1);
}

extern "C" void kernel_launch(void* const* d_in, const int* in_sizes, int n_in,
                              void* d_out, int out_size, void* d_ws, size_t ws_size,
                              hipStream_t stream) {
    const float* x  = (const float*)d_in[0];   // [N,64]
    const int*   ei = (const int*)d_in[1];     // [2,E] row-major: src then dst
    const float* W1 = (const float*)d_in[2];   // [64,64]
    const float* b1 = (const float*)d_in[3];   // [64]
    const float* W2 = (const float*)d_in[4];   // [64,32]
    const float* b2 = (const float*)d_in[5];   // [32]

    const int* srcp = ei;
    const int* dstp = ei + E_EDGES;

    // tuple return order: (out [N,32], feature_map [N,64]) concatenated flat
    float* out = (float*)d_out;                   // N*32
    float* fm  = (float*)d_out + N_NODES * 32;    // N*64 (also h1 input to layer 2)

    // workspace layout
    char* w = (char*)d_ws;
    int*      deg     = (int*)w;       w += sizeof(int) * N_NODES;
    int*      rowptr  = (int*)w;       w += sizeof(int) * N_NODES;
    int*      bsum    = (int*)w;       w += sizeof(int) * 512;
    int*      gcursor = (int*)w;       w += sizeof(int) * NBUCK;
    float*    dinv    = (float*)w;     w += sizeof(float) * N_NODES;
    int*      csrc    = (int*)w;       w += sizeof(int) * E_EDGES;
    unsigned* staged  = (unsigned*)w;  w += sizeof(unsigned) * E_EDGES;
    unsigned* HS1     = (unsigned*)w;  w += sizeof(unsigned) * (size_t)N_NODES * 32;
    unsigned* HS2     = (unsigned*)w;  w += sizeof(unsigned) * (size_t)N_NODES * 16;

    hipMemsetAsync(deg, 0, sizeof(int) * N_NODES, stream);

    // ---- graph preprocessing (shared by both layers) ----
    deg_kernel<<<(E_EDGES + 255) / 256, 256, 0, stream>>>(dstp, deg, E_EDGES);
    dinv_kernel<<<(N_NODES + 255) / 256, 256, 0, stream>>>(deg, dinv, N_NODES);
    scan1_kernel<<<NB_SCAN, SCAN_BLK, 0, stream>>>(deg, rowptr, bsum, N_NODES);
    scan2_kernel<<<1, 512, 0, stream>>>(bsum, NB_SCAN);
    scan3_kernel<<<NB_SCAN, SCAN_BLK, 0, stream>>>(rowptr, bsum, N_NODES);
    cursor_init_kernel<<<(NBUCK + 255) / 256, 256, 0, stream>>>(rowptr, gcursor);
    stage_kernel<<<(E_EDGES + STAGE_CHUNK - 1) / STAGE_CHUNK, STAGE_TPB, 0, stream>>>(
        srcp, dstp, gcursor, staged, E_EDGES);
    bucket_csr_kernel<<<NBUCK, 256, 0, stream>>>(staged, rowptr, deg, csrc, N_NODES, E_EDGES);

    // ---- layer 1: HS1 = bf16((x@W1)*dinv); fm = relu(gather) ----
    linear_kernel<64><<<(N_NODES + 7) / 8, 256, 0, stream>>>(x, W1, dinv, HS1, N_NODES);
    gather_kernel<64, true><<<(N_NODES + 7) / 8, 256, 0, stream>>>(
        rowptr, deg, csrc, HS1, dinv, b1, fm, N_NODES);

    // ---- layer 2: HS2 = bf16((fm@W2)*dinv); out = gather ----
    linear_kernel<32><<<(N_NODES + 15) / 16, 256, 0, stream>>>(fm, W2, dinv, HS2, N_NODES);
    gather_kernel<32, false><<<(N_NODES + 15) / 16, 256, 0, stream>>>(
        rowptr, deg, csrc, HS2, dinv, b2, out, N_NODES);
}

// Round 5
// 278.846 us; speedup vs baseline: 2.8359x; 1.1955x over previous
//
#include <hip/hip_runtime.h>

#define N_NODES 100000
#define E_EDGES 1600000

// bucketed CSR build
#define BSHIFT 7
#define BSIZE 128
#define NBUCK ((N_NODES + BSIZE - 1) / BSIZE)           // 782
#define STAGE_TPB 1024
#define STAGE_EPT 8
#define STAGE_CHUNK (STAGE_TPB * STAGE_EPT)             // 8192
#define HIST_TPB 256
#define HIST_EPT 32
#define HIST_CHUNK (HIST_TPB * HIST_EPT)                // 8192
#define BUCKET_CAP 4096                                  // >> max bucket edges (~2300)

// ---- bf16x2 pack/unpack (RNE) ----
__device__ inline unsigned pack_bf16x2(float a, float b) {
    union { float f; unsigned u; } ua, ub;
    ua.f = a; ub.f = b;
    unsigned ra = (ua.u + 0x7fffu + ((ua.u >> 16) & 1u)) >> 16;
    unsigned rb = (ub.u + 0x7fffu + ((ub.u >> 16) & 1u)) >> 16;
    return ra | (rb << 16);
}
__device__ inline float bf_lo(unsigned u) { union { unsigned u; float f; } t; t.u = u << 16; return t.f; }
__device__ inline float bf_hi(unsigned u) { union { unsigned u; float f; } t; t.u = u & 0xffff0000u; return t.f; }

// ---------------- coarse bucket histogram (LDS-staged) ----------------
__global__ void bucket_hist_kernel(const int* __restrict__ dst, int* __restrict__ bhist, int E) {
    __shared__ int h[NBUCK];
    const int tid = threadIdx.x;
    for (int i = tid; i < NBUCK; i += HIST_TPB) h[i] = 0;
    __syncthreads();
    const int e0 = blockIdx.x * HIST_CHUNK;
#pragma unroll
    for (int k = 0; k < HIST_EPT; ++k) {
        int e = e0 + k * HIST_TPB + tid;
        if (e < E) atomicAdd(&h[dst[e] >> BSHIFT], 1);
    }
    __syncthreads();
    for (int i = tid; i < NBUCK; i += HIST_TPB)
        if (h[i] > 0) atomicAdd(&bhist[i], h[i]);
}

// ---------------- single-block exclusive scan of bucket counts ----------------
// boff[b] (b in [0,NBUCK]) and stage cursors
__global__ void bscan_kernel(const int* __restrict__ bhist, int* __restrict__ boff,
                             int* __restrict__ gcursor) {
    __shared__ int s[1024];
    const int tid = threadIdx.x;
    int v = (tid < NBUCK) ? bhist[tid] : 0;
    s[tid] = v;
    __syncthreads();
    for (int off = 1; off < 1024; off <<= 1) {
        int t = (tid >= off) ? s[tid - off] : 0;
        __syncthreads();
        s[tid] += t;
        __syncthreads();
    }
    if (tid < NBUCK) {
        int ex = s[tid] - v;
        boff[tid] = ex;
        gcursor[tid] = ex;
    }
    if (tid == NBUCK - 1) boff[NBUCK] = s[tid];  // == E
}

// ---------------- stage edges into bucket-major order ----------------
// record = src | ((dst & 127) << 17); src < 2^17
__global__ void __launch_bounds__(STAGE_TPB) stage_kernel(
    const int* __restrict__ src, const int* __restrict__ dst,
    int* __restrict__ gcursor, unsigned* __restrict__ staged, int E) {
    __shared__ int hist[NBUCK];
    __shared__ int base[NBUCK];
    __shared__ int cnt2[NBUCK];
    const int tid = threadIdx.x;
    const int e0 = blockIdx.x * STAGE_CHUNK;
    for (int i = tid; i < NBUCK; i += STAGE_TPB) { hist[i] = 0; cnt2[i] = 0; }
    __syncthreads();
    int d[STAGE_EPT], s[STAGE_EPT];
#pragma unroll
    for (int k = 0; k < STAGE_EPT; ++k) {
        int e = e0 + k * STAGE_TPB + tid;
        if (e < E) {
            d[k] = dst[e];
            s[k] = src[e];
            atomicAdd(&hist[d[k] >> BSHIFT], 1);
        } else {
            d[k] = -1;
        }
    }
    __syncthreads();
    for (int i = tid; i < NBUCK; i += STAGE_TPB)
        if (hist[i] > 0) base[i] = atomicAdd(&gcursor[i], hist[i]);
    __syncthreads();
#pragma unroll
    for (int k = 0; k < STAGE_EPT; ++k) {
        if (d[k] >= 0) {
            int b = d[k] >> BSHIFT;
            int pos = base[b] + atomicAdd(&cnt2[b], 1);
            staged[pos] = (unsigned)s[k] | ((unsigned)(d[k] & (BSIZE - 1)) << 17);
        }
    }
}

// ---------------- per-bucket: deg/dinv/rowptr + fine CSR, all coalesced ----------------
__global__ void bucket_csr_kernel(const unsigned* __restrict__ staged,
                                  const int* __restrict__ boff,
                                  int* __restrict__ deg, float* __restrict__ dinv,
                                  int* __restrict__ rowptr, int* __restrict__ csrc, int n) {
    __shared__ int ldeg[BSIZE];
    __shared__ int lrp[BSIZE];
    __shared__ int lcnt[BSIZE];
    __shared__ unsigned lrec[BUCKET_CAP];
    __shared__ int lsrc[BUCKET_CAP];
    const int b = blockIdx.x;
    const int node0 = b * BSIZE;
    const int nn = min(BSIZE, n - node0);
    const int tid = threadIdx.x;  // 256
    if (tid < BSIZE) { ldeg[tid] = 0; lcnt[tid] = 0; }
    __syncthreads();
    const int ebase = boff[b];
    const int eend = boff[b + 1];
    const int ecnt = eend - ebase;
    for (int i = tid; i < ecnt; i += 256) {
        unsigned r = staged[ebase + i];
        if (i < BUCKET_CAP) lrec[i] = r;
        atomicAdd(&ldeg[r >> 17], 1);
    }
    __syncthreads();
    int mydeg = (tid < BSIZE) ? ldeg[tid] : 0;
    if (tid < BSIZE) lrp[tid] = mydeg;
    __syncthreads();
    // inclusive scan over BSIZE entries
    for (int off = 1; off < BSIZE; off <<= 1) {
        int v = 0;
        if (tid < BSIZE && tid >= off) v = lrp[tid - off];
        __syncthreads();
        if (tid < BSIZE) lrp[tid] += v;
        __syncthreads();
    }
    if (tid < BSIZE) {
        int ex = lrp[tid] - mydeg;  // exclusive
        lrp[tid] = ex;
        if (tid < nn) {
            deg[node0 + tid] = mydeg;
            dinv[node0 + tid] = rsqrtf((float)mydeg + 2.0f);
            rowptr[node0 + tid] = ebase + ex;
        }
    }
    __syncthreads();
    for (int i = tid; i < ecnt; i += 256) {
        unsigned r = lrec[i];
        int dl = (int)(r >> 17);
        int sv = (int)(r & 0x1FFFFu);
        int pos = lrp[dl] + atomicAdd(&lcnt[dl], 1);
        if (pos < BUCKET_CAP) lsrc[pos] = sv;
    }
    __syncthreads();
    for (int i = tid; i < ecnt; i += 256)
        csrc[ebase + i] = lsrc[i];
}

// ---------------- dense linear + dinv-scale + bf16x2 pack ----------------
template <int FOUT>
__global__ void linear_kernel(const float* __restrict__ X, const float* __restrict__ W,
                              const float* __restrict__ dinv, unsigned* __restrict__ HS, int n) {
    constexpr int CP = FOUT / 2;       // col pairs
    constexpr int RPB = 256 / CP;      // rows per block
    __shared__ float Ws[64 * FOUT];
    __shared__ float Xs[RPB][64];
    const int tid = threadIdx.x;
    for (int i = tid; i < 64 * FOUT; i += 256) Ws[i] = W[i];
    const int row0 = blockIdx.x * RPB;
    for (int i = tid; i < RPB * 64; i += 256) {
        int r = row0 + (i >> 6);
        Xs[i >> 6][i & 63] = (r < n) ? X[r * 64 + (i & 63)] : 0.0f;
    }
    __syncthreads();
    const int rl = tid / CP;
    const int c  = tid % CP;
    const int row = row0 + rl;
    if (row >= n) return;
    float acc0 = 0.0f, acc1 = 0.0f;
#pragma unroll
    for (int k = 0; k < 64; ++k) {
        float xv = Xs[rl][k];
        acc0 += xv * Ws[k * FOUT + 2 * c];
        acc1 += xv * Ws[k * FOUT + 2 * c + 1];
    }
    float d = dinv[row];
    HS[(size_t)row * CP + c] = pack_bf16x2(acc0 * d, acc1 * d);
}

// ---------------- fused gather + self-loop + bias (+ReLU) ----------------
template <int F, bool RELU>
__global__ void gather_kernel(const int* __restrict__ rowptr, const int* __restrict__ deg,
                              const int* __restrict__ csrc, const unsigned* __restrict__ HS,
                              const float* __restrict__ dinv, const float* __restrict__ bias,
                              float* __restrict__ OUT, int n) {
    constexpr int G = F / 2;
    constexpr int NPB = 256 / G;
    int node = blockIdx.x * NPB + (threadIdx.x / G);
    int l = threadIdx.x % G;
    if (node >= n) return;
    int start = rowptr[node];
    int cnt = deg[node];
    unsigned us = HS[(size_t)node * G + l];
    float a0 = 2.0f * bf_lo(us);
    float a1 = 2.0f * bf_hi(us);
    int j = start, end = start + cnt;
    for (; j + 3 < end; j += 4) {
        int s0 = csrc[j], s1 = csrc[j + 1], s2 = csrc[j + 2], s3 = csrc[j + 3];
        unsigned u0 = HS[(size_t)s0 * G + l];
        unsigned u1 = HS[(size_t)s1 * G + l];
        unsigned u2 = HS[(size_t)s2 * G + l];
        unsigned u3 = HS[(size_t)s3 * G + l];
        a0 += bf_lo(u0) + bf_lo(u1) + bf_lo(u2) + bf_lo(u3);
        a1 += bf_hi(u0) + bf_hi(u1) + bf_hi(u2) + bf_hi(u3);
    }
    for (; j < end; ++j) {
        unsigned u = HS[(size_t)csrc[j] * G + l];
        a0 += bf_lo(u);
        a1 += bf_hi(u);
    }
    float dd = dinv[node];
    float2 bb = ((const float2*)bias)[l];
    float o0 = a0 * dd + bb.x;
    float o1 = a1 * dd + bb.y;
    if (RELU) { o0 = fmaxf(o0, 0.0f); o1 = fmaxf(o1, 0.0f); }
    ((float2*)OUT)[(size_t)node * G + l] = make_float2(o0, o1);
}

extern "C" void kernel_launch(void* const* d_in, const int* in_sizes, int n_in,
                              void* d_out, int out_size, void* d_ws, size_t ws_size,
                              hipStream_t stream) {
    const float* x  = (const float*)d_in[0];   // [N,64]
    const int*   ei = (const int*)d_in[1];     // [2,E] row-major: src then dst
    const float* W1 = (const float*)d_in[2];   // [64,64]
    const float* b1 = (const float*)d_in[3];   // [64]
    const float* W2 = (const float*)d_in[4];   // [64,32]
    const float* b2 = (const float*)d_in[5];   // [32]

    const int* srcp = ei;
    const int* dstp = ei + E_EDGES;

    // tuple return order: (out [N,32], feature_map [N,64]) concatenated flat
    float* out = (float*)d_out;                   // N*32
    float* fm  = (float*)d_out + N_NODES * 32;    // N*64 (also h1 input to layer 2)

    // workspace layout
    char* w = (char*)d_ws;
    int*      bhist   = (int*)w;       w += sizeof(int) * NBUCK;
    int*      boff    = (int*)w;       w += sizeof(int) * (NBUCK + 1);
    int*      gcursor = (int*)w;       w += sizeof(int) * NBUCK;
    int*      deg     = (int*)w;       w += sizeof(int) * N_NODES;
    int*      rowptr  = (int*)w;       w += sizeof(int) * N_NODES;
    float*    dinv    = (float*)w;     w += sizeof(float) * N_NODES;
    int*      csrc    = (int*)w;       w += sizeof(int) * E_EDGES;
    unsigned* staged  = (unsigned*)w;  w += sizeof(unsigned) * E_EDGES;
    unsigned* HS1     = (unsigned*)w;  w += sizeof(unsigned) * (size_t)N_NODES * 32;
    unsigned* HS2     = (unsigned*)w;  w += sizeof(unsigned) * (size_t)N_NODES * 16;

    hipMemsetAsync(bhist, 0, sizeof(int) * NBUCK, stream);

    // ---- graph preprocessing (shared by both layers) ----
    bucket_hist_kernel<<<(E_EDGES + HIST_CHUNK - 1) / HIST_CHUNK, HIST_TPB, 0, stream>>>(
        dstp, bhist, E_EDGES);
    bscan_kernel<<<1, 1024, 0, stream>>>(bhist, boff, gcursor);
    stage_kernel<<<(E_EDGES + STAGE_CHUNK - 1) / STAGE_CHUNK, STAGE_TPB, 0, stream>>>(
        srcp, dstp, gcursor, staged, E_EDGES);
    bucket_csr_kernel<<<NBUCK, 256, 0, stream>>>(staged, boff, deg, dinv, rowptr, csrc, N_NODES);

    // ---- layer 1: HS1 = bf16((x@W1)*dinv); fm = relu(gather) ----
    linear_kernel<64><<<(N_NODES + 7) / 8, 256, 0, stream>>>(x, W1, dinv, HS1, N_NODES);
    gather_kernel<64, true><<<(N_NODES + 7) / 8, 256, 0, stream>>>(
        rowptr, deg, csrc, HS1, dinv, b1, fm, N_NODES);

    // ---- layer 2: HS2 = bf16((fm@W2)*dinv); out = gather ----
    linear_kernel<32><<<(N_NODES + 15) / 16, 256, 0, stream>>>(fm, W2, dinv, HS2, N_NODES);
    gather_kernel<32, false><<<(N_NODES + 15) / 16, 256, 0, stream>>>(
        rowptr, deg, csrc, HS2, dinv, b2, out, N_NODES);
}

// Round 6
// 276.626 us; speedup vs baseline: 2.8586x; 1.0080x over previous
//
#include <hip/hip_runtime.h>

#define N_NODES 100000
#define E_EDGES 1600000

// bucketed CSR build
#define BSHIFT 7
#define BSIZE 128
#define NBUCK ((N_NODES + BSIZE - 1) / BSIZE)           // 782
#define STAGE_TPB 1024
#define STAGE_EPT 16
#define STAGE_CHUNK (STAGE_TPB * STAGE_EPT)             // 16384
#define BUCKET_CAP 4096                                  // staged slots per bucket (mean 2046)

// ---- bf16x2 pack/unpack (RNE) ----
__device__ inline unsigned pack_bf16x2(float a, float b) {
    union { float f; unsigned u; } ua, ub;
    ua.f = a; ub.f = b;
    unsigned ra = (ua.u + 0x7fffu + ((ua.u >> 16) & 1u)) >> 16;
    unsigned rb = (ub.u + 0x7fffu + ((ub.u >> 16) & 1u)) >> 16;
    return ra | (rb << 16);
}
__device__ inline float bf_lo(unsigned u) { union { unsigned u; float f; } t; t.u = u << 16; return t.f; }
__device__ inline float bf_hi(unsigned u) { union { unsigned u; float f; } t; t.u = u & 0xffff0000u; return t.f; }

// ---------------- cursor init: gcursor[b] = b * BUCKET_CAP ----------------
__global__ void cursor_init_kernel(int* __restrict__ gcursor) {
    int b = blockIdx.x * blockDim.x + threadIdx.x;
    if (b < NBUCK) gcursor[b] = b * BUCKET_CAP;
}

// ---------------- stage edges into fixed-capacity bucket regions ----------------
// record = src | ((dst & 127) << 17); src < 2^17
__global__ void __launch_bounds__(STAGE_TPB) stage_kernel(
    const int* __restrict__ src, const int* __restrict__ dst,
    int* __restrict__ gcursor, unsigned* __restrict__ staged, int E) {
    __shared__ int hist[NBUCK];
    __shared__ int base[NBUCK];
    __shared__ int cnt2[NBUCK];
    const int tid = threadIdx.x;
    const int e0 = blockIdx.x * STAGE_CHUNK;
    for (int i = tid; i < NBUCK; i += STAGE_TPB) { hist[i] = 0; cnt2[i] = 0; }
    __syncthreads();
    int d[STAGE_EPT], s[STAGE_EPT];
#pragma unroll
    for (int k = 0; k < STAGE_EPT; ++k) {
        int e = e0 + k * STAGE_TPB + tid;
        if (e < E) {
            d[k] = dst[e];
            s[k] = src[e];
            atomicAdd(&hist[d[k] >> BSHIFT], 1);
        } else {
            d[k] = -1;
        }
    }
    __syncthreads();
    for (int i = tid; i < NBUCK; i += STAGE_TPB)
        if (hist[i] > 0) base[i] = atomicAdd(&gcursor[i], hist[i]);
    __syncthreads();
#pragma unroll
    for (int k = 0; k < STAGE_EPT; ++k) {
        if (d[k] >= 0) {
            int b = d[k] >> BSHIFT;
            int pos = base[b] + atomicAdd(&cnt2[b], 1);
            if (pos < (b + 1) * BUCKET_CAP)  // statistically never false; memory-safety clamp
                staged[pos] = (unsigned)s[k] | ((unsigned)(d[k] & (BSIZE - 1)) << 17);
        }
    }
}

// ---------------- post-stage scan: counts from cursors -> boff ----------------
__global__ void bscan_kernel(const int* __restrict__ gcursor, int* __restrict__ boff) {
    __shared__ int s[1024];
    const int tid = threadIdx.x;
    int v = 0;
    if (tid < NBUCK) {
        v = gcursor[tid] - tid * BUCKET_CAP;   // bucket count
        if (v > BUCKET_CAP) v = BUCKET_CAP;
    }
    s[tid] = v;
    __syncthreads();
    for (int off = 1; off < 1024; off <<= 1) {
        int t = (tid >= off) ? s[tid - off] : 0;
        __syncthreads();
        s[tid] += t;
        __syncthreads();
    }
    if (tid < NBUCK) boff[tid] = s[tid] - v;  // exclusive
    if (tid == NBUCK - 1) boff[NBUCK] = s[tid];
}

// ---------------- per-bucket: deg/dinv/rowptr + fine CSR, all coalesced ----------------
__global__ void bucket_csr_kernel(const unsigned* __restrict__ staged,
                                  const int* __restrict__ boff,
                                  int* __restrict__ deg, float* __restrict__ dinv,
                                  int* __restrict__ rowptr, int* __restrict__ csrc, int n) {
    __shared__ int ldeg[BSIZE];
    __shared__ int lrp[BSIZE];
    __shared__ int lcnt[BSIZE];
    __shared__ unsigned lrec[BUCKET_CAP];
    __shared__ int lsrc[BUCKET_CAP];
    const int b = blockIdx.x;
    const int node0 = b * BSIZE;
    const int nn = min(BSIZE, n - node0);
    const int tid = threadIdx.x;  // 256
    if (tid < BSIZE) { ldeg[tid] = 0; lcnt[tid] = 0; }
    __syncthreads();
    const int ebase = boff[b];
    const int ecnt = min(boff[b + 1] - ebase, BUCKET_CAP);
    const int sbase = b * BUCKET_CAP;
    for (int i = tid; i < ecnt; i += 256) {
        unsigned r = staged[sbase + i];
        lrec[i] = r;
        atomicAdd(&ldeg[r >> 17], 1);
    }
    __syncthreads();
    int mydeg = (tid < BSIZE) ? ldeg[tid] : 0;
    if (tid < BSIZE) lrp[tid] = mydeg;
    __syncthreads();
    for (int off = 1; off < BSIZE; off <<= 1) {
        int v = 0;
        if (tid < BSIZE && tid >= off) v = lrp[tid - off];
        __syncthreads();
        if (tid < BSIZE) lrp[tid] += v;
        __syncthreads();
    }
    if (tid < BSIZE) {
        int ex = lrp[tid] - mydeg;  // exclusive
        lrp[tid] = ex;
        if (tid < nn) {
            deg[node0 + tid] = mydeg;
            dinv[node0 + tid] = rsqrtf((float)mydeg + 2.0f);
            rowptr[node0 + tid] = ebase + ex;
        }
    }
    __syncthreads();
    for (int i = tid; i < ecnt; i += 256) {
        unsigned r = lrec[i];
        int dl = (int)(r >> 17);
        int sv = (int)(r & 0x1FFFFu);
        int pos = lrp[dl] + atomicAdd(&lcnt[dl], 1);
        if (pos < BUCKET_CAP) lsrc[pos] = sv;
    }
    __syncthreads();
    for (int i = tid; i < ecnt; i += 256)
        csrc[ebase + i] = lsrc[i];
}

// ---------------- dense linear + dinv-scale + bf16x2 pack, feature-chunked output ----------------
// HS chunk arrays: HS[chunk][row][16 uints] (32 features per chunk), chunk stride = n*16
template <int FOUT>
__global__ void linear_kernel(const float* __restrict__ X, const float* __restrict__ W,
                              const float* __restrict__ dinv, unsigned* __restrict__ HS, int n) {
    constexpr int CP = FOUT / 2;       // col pairs (uints per row)
    constexpr int RPB = 256 / CP;      // rows per block
    __shared__ float Ws[64 * FOUT];
    __shared__ float Xs[RPB][64];
    const int tid = threadIdx.x;
    for (int i = tid; i < 64 * FOUT; i += 256) Ws[i] = W[i];
    const int row0 = blockIdx.x * RPB;
    for (int i = tid; i < RPB * 64; i += 256) {
        int r = row0 + (i >> 6);
        Xs[i >> 6][i & 63] = (r < n) ? X[r * 64 + (i & 63)] : 0.0f;
    }
    __syncthreads();
    const int rl = tid / CP;
    const int c  = tid % CP;
    const int row = row0 + rl;
    if (row >= n) return;
    float acc0 = 0.0f, acc1 = 0.0f;
#pragma unroll
    for (int k = 0; k < 64; ++k) {
        float xv = Xs[rl][k];
        acc0 += xv * Ws[k * FOUT + 2 * c];
        acc1 += xv * Ws[k * FOUT + 2 * c + 1];
    }
    float d = dinv[row];
    // chunked layout: chunk = c/16, within-chunk uint index = c%16
    unsigned* dst = HS + (size_t)(c >> 4) * n * 16 + (size_t)row * 16 + (c & 15);
    *dst = pack_bf16x2(acc0 * d, acc1 * d);
}

// ---------------- fused gather over one 32-feature chunk ----------------
// G=16 lanes/node, each lane owns 2 feats; HS row = 16 uints = 64 B (one line).
// OUT[node*out_stride_f2 + out_off_f2 + l] (float2)
template <bool RELU>
__global__ void gather_chunk_kernel(const int* __restrict__ rowptr, const int* __restrict__ deg,
                                    const int* __restrict__ csrc, const unsigned* __restrict__ HS,
                                    const float* __restrict__ dinv, const float* __restrict__ bias,
                                    float* __restrict__ OUT, int out_stride_f2, int out_off_f2,
                                    int n) {
    constexpr int G = 16;
    constexpr int NPB = 256 / G;  // 16 nodes per block
    int node = blockIdx.x * NPB + (threadIdx.x / G);
    int l = threadIdx.x % G;
    if (node >= n) return;
    int start = rowptr[node];
    int cnt = deg[node];
    unsigned us = HS[(size_t)node * G + l];
    float a0 = 2.0f * bf_lo(us);
    float a1 = 2.0f * bf_hi(us);
    int j = start, end = start + cnt;
    for (; j + 3 < end; j += 4) {
        int s0 = csrc[j], s1 = csrc[j + 1], s2 = csrc[j + 2], s3 = csrc[j + 3];
        unsigned u0 = HS[(size_t)s0 * G + l];
        unsigned u1 = HS[(size_t)s1 * G + l];
        unsigned u2 = HS[(size_t)s2 * G + l];
        unsigned u3 = HS[(size_t)s3 * G + l];
        a0 += bf_lo(u0) + bf_lo(u1) + bf_lo(u2) + bf_lo(u3);
        a1 += bf_hi(u0) + bf_hi(u1) + bf_hi(u2) + bf_hi(u3);
    }
    for (; j < end; ++j) {
        unsigned u = HS[(size_t)csrc[j] * G + l];
        a0 += bf_lo(u);
        a1 += bf_hi(u);
    }
    float dd = dinv[node];
    float2 bb = ((const float2*)bias)[l];
    float o0 = a0 * dd + bb.x;
    float o1 = a1 * dd + bb.y;
    if (RELU) { o0 = fmaxf(o0, 0.0f); o1 = fmaxf(o1, 0.0f); }
    ((float2*)OUT)[(size_t)node * out_stride_f2 + out_off_f2 + l] = make_float2(o0, o1);
}

extern "C" void kernel_launch(void* const* d_in, const int* in_sizes, int n_in,
                              void* d_out, int out_size, void* d_ws, size_t ws_size,
                              hipStream_t stream) {
    const float* x  = (const float*)d_in[0];   // [N,64]
    const int*   ei = (const int*)d_in[1];     // [2,E] row-major: src then dst
    const float* W1 = (const float*)d_in[2];   // [64,64]
    const float* b1 = (const float*)d_in[3];   // [64]
    const float* W2 = (const float*)d_in[4];   // [64,32]
    const float* b2 = (const float*)d_in[5];   // [32]

    const int* srcp = ei;
    const int* dstp = ei + E_EDGES;

    // tuple return order: (out [N,32], feature_map [N,64]) concatenated flat
    float* out = (float*)d_out;                   // N*32
    float* fm  = (float*)d_out + N_NODES * 32;    // N*64 (also h1 input to layer 2)

    // workspace layout
    char* w = (char*)d_ws;
    int*      gcursor = (int*)w;       w += sizeof(int) * NBUCK;
    int*      boff    = (int*)w;       w += sizeof(int) * (NBUCK + 1);
    int*      deg     = (int*)w;       w += sizeof(int) * N_NODES;
    int*      rowptr  = (int*)w;       w += sizeof(int) * N_NODES;
    float*    dinv    = (float*)w;     w += sizeof(float) * N_NODES;
    int*      csrc    = (int*)w;       w += sizeof(int) * E_EDGES;
    unsigned* staged  = (unsigned*)w;  w += sizeof(unsigned) * (size_t)NBUCK * BUCKET_CAP;
    unsigned* HS1     = (unsigned*)w;  w += sizeof(unsigned) * (size_t)N_NODES * 32;  // 2 chunks x N x 16
    unsigned* HS2     = (unsigned*)w;  w += sizeof(unsigned) * (size_t)N_NODES * 16;  // 1 chunk

    // ---- graph preprocessing (shared by both layers) ----
    cursor_init_kernel<<<(NBUCK + 255) / 256, 256, 0, stream>>>(gcursor);
    stage_kernel<<<(E_EDGES + STAGE_CHUNK - 1) / STAGE_CHUNK, STAGE_TPB, 0, stream>>>(
        srcp, dstp, gcursor, staged, E_EDGES);
    bscan_kernel<<<1, 1024, 0, stream>>>(gcursor, boff);
    bucket_csr_kernel<<<NBUCK, 256, 0, stream>>>(staged, boff, deg, dinv, rowptr, csrc, N_NODES);

    // ---- layer 1: HS1 = bf16((x@W1)*dinv) in 2 chunks; fm = relu(gather) per chunk ----
    linear_kernel<64><<<(N_NODES + 7) / 8, 256, 0, stream>>>(x, W1, dinv, HS1, N_NODES);
    gather_chunk_kernel<true><<<(N_NODES + 15) / 16, 256, 0, stream>>>(
        rowptr, deg, csrc, HS1, dinv, b1, fm, 32, 0, N_NODES);
    gather_chunk_kernel<true><<<(N_NODES + 15) / 16, 256, 0, stream>>>(
        rowptr, deg, csrc, HS1 + (size_t)N_NODES * 16, dinv, b1 + 32, fm, 32, 16, N_NODES);

    // ---- layer 2: HS2 = bf16((fm@W2)*dinv); out = gather (single 32-feat chunk) ----
    linear_kernel<32><<<(N_NODES + 15) / 16, 256, 0, stream>>>(fm, W2, dinv, HS2, N_NODES);
    gather_chunk_kernel<false><<<(N_NODES + 15) / 16, 256, 0, stream>>>(
        rowptr, deg, csrc, HS2, dinv, b2, out, 16, 0, N_NODES);
}

// Round 7
// 234.093 us; speedup vs baseline: 3.3780x; 1.1817x over previous
//
#include <hip/hip_runtime.h>

#define N_NODES 100000
#define E_EDGES 1600000

// bucketed CSR build
#define BSHIFT 7
#define BSIZE 128
#define NBUCK ((N_NODES + BSIZE - 1) / BSIZE)           // 782
#define STAGE_TPB 1024
#define STAGE_EPT 16
#define STAGE_CHUNK (STAGE_TPB * STAGE_EPT)             // 16384
#define BUCKET_CAP 4096                                  // staged slots per bucket (mean 2046)

typedef __attribute__((ext_vector_type(8))) short short8;
typedef __attribute__((ext_vector_type(4))) float float4v;

// ---- bf16 helpers (RNE) ----
__device__ inline unsigned short f2bf(float f) {
    union { float f; unsigned u; } t; t.f = f;
    unsigned r = (t.u + 0x7fffu + ((t.u >> 16) & 1u)) >> 16;
    return (unsigned short)r;
}
__device__ inline float bf2f(unsigned short h) {
    union { unsigned u; float f; } t; t.u = ((unsigned)h) << 16; return t.f;
}
__device__ inline unsigned pack_bf16x2(float a, float b) {
    return (unsigned)f2bf(a) | ((unsigned)f2bf(b) << 16);
}
__device__ inline float bf_lo(unsigned u) { union { unsigned u; float f; } t; t.u = u << 16; return t.f; }
__device__ inline float bf_hi(unsigned u) { union { unsigned u; float f; } t; t.u = u & 0xffff0000u; return t.f; }

// ---------------- cursor init: gcursor[b] = b * BUCKET_CAP ----------------
__global__ void cursor_init_kernel(int* __restrict__ gcursor) {
    int b = blockIdx.x * blockDim.x + threadIdx.x;
    if (b < NBUCK) gcursor[b] = b * BUCKET_CAP;
}

// ---------------- stage edges into fixed-capacity bucket regions ----------------
// record = src | ((dst & 127) << 17); src < 2^17
__global__ void __launch_bounds__(STAGE_TPB) stage_kernel(
    const int* __restrict__ src, const int* __restrict__ dst,
    int* __restrict__ gcursor, unsigned* __restrict__ staged, int E) {
    __shared__ int hist[NBUCK];
    __shared__ int base[NBUCK];
    __shared__ int cnt2[NBUCK];
    const int tid = threadIdx.x;
    const int e0 = blockIdx.x * STAGE_CHUNK;
    for (int i = tid; i < NBUCK; i += STAGE_TPB) { hist[i] = 0; cnt2[i] = 0; }
    __syncthreads();
    int d[STAGE_EPT], s[STAGE_EPT];
#pragma unroll
    for (int k = 0; k < STAGE_EPT; ++k) {
        int e = e0 + k * STAGE_TPB + tid;
        if (e < E) {
            d[k] = dst[e];
            s[k] = src[e];
            atomicAdd(&hist[d[k] >> BSHIFT], 1);
        } else {
            d[k] = -1;
        }
    }
    __syncthreads();
    for (int i = tid; i < NBUCK; i += STAGE_TPB)
        if (hist[i] > 0) base[i] = atomicAdd(&gcursor[i], hist[i]);
    __syncthreads();
#pragma unroll
    for (int k = 0; k < STAGE_EPT; ++k) {
        if (d[k] >= 0) {
            int b = d[k] >> BSHIFT;
            int pos = base[b] + atomicAdd(&cnt2[b], 1);
            if (pos < (b + 1) * BUCKET_CAP)  // statistically never false; memory-safety clamp
                staged[pos] = (unsigned)s[k] | ((unsigned)(d[k] & (BSIZE - 1)) << 17);
        }
    }
}

// ---------------- post-stage scan: counts from cursors -> boff ----------------
__global__ void bscan_kernel(const int* __restrict__ gcursor, int* __restrict__ boff) {
    __shared__ int s[1024];
    const int tid = threadIdx.x;
    int v = 0;
    if (tid < NBUCK) {
        v = gcursor[tid] - tid * BUCKET_CAP;   // bucket count
        if (v > BUCKET_CAP) v = BUCKET_CAP;
    }
    s[tid] = v;
    __syncthreads();
    for (int off = 1; off < 1024; off <<= 1) {
        int t = (tid >= off) ? s[tid - off] : 0;
        __syncthreads();
        s[tid] += t;
        __syncthreads();
    }
    if (tid < NBUCK) boff[tid] = s[tid] - v;  // exclusive
    if (tid == NBUCK - 1) boff[NBUCK] = s[tid];
}

// ---------------- per-bucket: deg/dinv/rowptr + fine CSR, all coalesced ----------------
__global__ void bucket_csr_kernel(const unsigned* __restrict__ staged,
                                  const int* __restrict__ boff,
                                  int* __restrict__ deg, float* __restrict__ dinv,
                                  int* __restrict__ rowptr, int* __restrict__ csrc, int n) {
    __shared__ int ldeg[BSIZE];
    __shared__ int lrp[BSIZE];
    __shared__ int lcnt[BSIZE];
    __shared__ unsigned lrec[BUCKET_CAP];
    __shared__ int lsrc[BUCKET_CAP];
    const int b = blockIdx.x;
    const int node0 = b * BSIZE;
    const int nn = min(BSIZE, n - node0);
    const int tid = threadIdx.x;  // 256
    if (tid < BSIZE) { ldeg[tid] = 0; lcnt[tid] = 0; }
    __syncthreads();
    const int ebase = boff[b];
    const int ecnt = min(boff[b + 1] - ebase, BUCKET_CAP);
    const int sbase = b * BUCKET_CAP;
    for (int i = tid; i < ecnt; i += 256) {
        unsigned r = staged[sbase + i];
        lrec[i] = r;
        atomicAdd(&ldeg[r >> 17], 1);
    }
    __syncthreads();
    int mydeg = (tid < BSIZE) ? ldeg[tid] : 0;
    if (tid < BSIZE) lrp[tid] = mydeg;
    __syncthreads();
    for (int off = 1; off < BSIZE; off <<= 1) {
        int v = 0;
        if (tid < BSIZE && tid >= off) v = lrp[tid - off];
        __syncthreads();
        if (tid < BSIZE) lrp[tid] += v;
        __syncthreads();
    }
    if (tid < BSIZE) {
        int ex = lrp[tid] - mydeg;  // exclusive
        lrp[tid] = ex;
        if (tid < nn) {
            deg[node0 + tid] = mydeg;
            dinv[node0 + tid] = rsqrtf((float)mydeg + 2.0f);
            rowptr[node0 + tid] = ebase + ex;
        }
    }
    __syncthreads();
    for (int i = tid; i < ecnt; i += 256) {
        unsigned r = lrec[i];
        int dl = (int)(r >> 17);
        int sv = (int)(r & 0x1FFFFu);
        int pos = lrp[dl] + atomicAdd(&lcnt[dl], 1);
        if (pos < BUCKET_CAP) lsrc[pos] = sv;
    }
    __syncthreads();
    for (int i = tid; i < ecnt; i += 256)
        csrc[ebase + i] = lsrc[i];
}

// ---------------- MFMA linear: HS = bf16x2((X@W)*dinv), chunked + (f,f+16) pairing ----------------
// Split GEMM: Ahi*Whi + Alo*Whi + Ahi*Wlo gives ~fp32 accuracy with bf16 MFMA.
// C/D layout (16x16x32_bf16): col=lane&15, row=(lane>>4)*4+reg.  A: [m=lane&15][k=(lane>>4)*8+j].
// HS chunk ch holds features [32ch,32ch+32); uint c of a row packs (feat 32ch+c, feat 32ch+16+c).
template <int FOUT>   // 64 or 32
__global__ void __launch_bounds__(256) linear_mfma_kernel(
    const float* __restrict__ X, const float* __restrict__ W,
    const float* __restrict__ dinv, unsigned* __restrict__ HS, int n) {
    constexpr int NT = FOUT / 16;            // n-tiles
    const int NTILES_M = n / 16;             // 6250 (n divisible by 16)
    const int lane = threadIdx.x & 63;
    const int gwave = blockIdx.x * 4 + (threadIdx.x >> 6);
    const int nwaves = gridDim.x * 4;
    const int m = lane & 15;
    const int q = lane >> 4;  // 0..3

    // W fragments in registers (hi+lo), loaded once per wave
    short8 Bhi[2][NT], Blo[2][NT];
#pragma unroll
    for (int ks = 0; ks < 2; ++ks)
#pragma unroll
        for (int nt = 0; nt < NT; ++nt) {
            short8 bh, bl;
#pragma unroll
            for (int j = 0; j < 8; ++j) {
                int k = ks * 32 + q * 8 + j;
                float wv = W[k * FOUT + nt * 16 + m];
                unsigned short h = f2bf(wv);
                bh[j] = (short)h;
                bl[j] = (short)f2bf(wv - bf2f(h));
            }
            Bhi[ks][nt] = bh;
            Blo[ks][nt] = bl;
        }

    for (int tile = gwave; tile < NTILES_M; tile += nwaves) {
        const int row0 = tile * 16;
        float4v C[NT];
#pragma unroll
        for (int nt = 0; nt < NT; ++nt) C[nt] = (float4v){0.f, 0.f, 0.f, 0.f};
#pragma unroll
        for (int ks = 0; ks < 2; ++ks) {
            const float* xp = X + (size_t)(row0 + m) * 64 + ks * 32 + q * 8;
            float4v x0 = *(const float4v*)xp;
            float4v x1 = *(const float4v*)(xp + 4);
            short8 Ahi, Alo;
#pragma unroll
            for (int j = 0; j < 4; ++j) {
                unsigned short h0 = f2bf(x0[j]);
                Ahi[j] = (short)h0;
                Alo[j] = (short)f2bf(x0[j] - bf2f(h0));
                unsigned short h1 = f2bf(x1[j]);
                Ahi[4 + j] = (short)h1;
                Alo[4 + j] = (short)f2bf(x1[j] - bf2f(h1));
            }
#pragma unroll
            for (int nt = 0; nt < NT; ++nt) {
                C[nt] = __builtin_amdgcn_mfma_f32_16x16x32_bf16(Ahi, Bhi[ks][nt], C[nt], 0, 0, 0);
                C[nt] = __builtin_amdgcn_mfma_f32_16x16x32_bf16(Alo, Bhi[ks][nt], C[nt], 0, 0, 0);
                C[nt] = __builtin_amdgcn_mfma_f32_16x16x32_bf16(Ahi, Blo[ks][nt], C[nt], 0, 0, 0);
            }
        }
        // epilogue: pair n-tile 2ch (cols 0-15) with 2ch+1 (cols 16-31) of chunk ch
#pragma unroll
        for (int ch = 0; ch < NT / 2; ++ch) {
#pragma unroll
            for (int reg = 0; reg < 4; ++reg) {
                int r = row0 + q * 4 + reg;
                float di = dinv[r];
                unsigned u = pack_bf16x2(C[2 * ch][reg] * di, C[2 * ch + 1][reg] * di);
                HS[(size_t)ch * n * 16 + (size_t)r * 16 + m] = u;
            }
        }
    }
}

// ---------------- fused gather over one 32-feature chunk ----------------
// G=16 lanes/node; uint l of a row = (feat base+l, feat base+16+l).
template <bool RELU>
__global__ void gather_chunk_kernel(const int* __restrict__ rowptr, const int* __restrict__ deg,
                                    const int* __restrict__ csrc, const unsigned* __restrict__ HS,
                                    const float* __restrict__ dinv, const float* __restrict__ bias0,
                                    float* __restrict__ OUT, int out_stride, int out_off,
                                    int n) {
    constexpr int G = 16;
    constexpr int NPB = 256 / G;  // 16 nodes per block
    int node = blockIdx.x * NPB + (threadIdx.x / G);
    int l = threadIdx.x % G;
    if (node >= n) return;
    int start = rowptr[node];
    int cnt = deg[node];
    unsigned us = HS[(size_t)node * G + l];
    float a0 = 2.0f * bf_lo(us);
    float a1 = 2.0f * bf_hi(us);
    int j = start, end = start + cnt;
    for (; j + 3 < end; j += 4) {
        int s0 = csrc[j], s1 = csrc[j + 1], s2 = csrc[j + 2], s3 = csrc[j + 3];
        unsigned u0 = HS[(size_t)s0 * G + l];
        unsigned u1 = HS[(size_t)s1 * G + l];
        unsigned u2 = HS[(size_t)s2 * G + l];
        unsigned u3 = HS[(size_t)s3 * G + l];
        a0 += bf_lo(u0) + bf_lo(u1) + bf_lo(u2) + bf_lo(u3);
        a1 += bf_hi(u0) + bf_hi(u1) + bf_hi(u2) + bf_hi(u3);
    }
    for (; j < end; ++j) {
        unsigned u = HS[(size_t)csrc[j] * G + l];
        a0 += bf_lo(u);
        a1 += bf_hi(u);
    }
    float dd = dinv[node];
    float o0 = a0 * dd + bias0[l];
    float o1 = a1 * dd + bias0[16 + l];
    if (RELU) { o0 = fmaxf(o0, 0.0f); o1 = fmaxf(o1, 0.0f); }
    OUT[(size_t)node * out_stride + out_off + l] = o0;
    OUT[(size_t)node * out_stride + out_off + 16 + l] = o1;
}

extern "C" void kernel_launch(void* const* d_in, const int* in_sizes, int n_in,
                              void* d_out, int out_size, void* d_ws, size_t ws_size,
                              hipStream_t stream) {
    const float* x  = (const float*)d_in[0];   // [N,64]
    const int*   ei = (const int*)d_in[1];     // [2,E] row-major: src then dst
    const float* W1 = (const float*)d_in[2];   // [64,64]
    const float* b1 = (const float*)d_in[3];   // [64]
    const float* W2 = (const float*)d_in[4];   // [64,32]
    const float* b2 = (const float*)d_in[5];   // [32]

    const int* srcp = ei;
    const int* dstp = ei + E_EDGES;

    // tuple return order: (out [N,32], feature_map [N,64]) concatenated flat
    float* out = (float*)d_out;                   // N*32
    float* fm  = (float*)d_out + N_NODES * 32;    // N*64 (also h1 input to layer 2)

    // workspace layout
    char* w = (char*)d_ws;
    int*      gcursor = (int*)w;       w += sizeof(int) * NBUCK;
    int*      boff    = (int*)w;       w += sizeof(int) * (NBUCK + 1);
    int*      deg     = (int*)w;       w += sizeof(int) * N_NODES;
    int*      rowptr  = (int*)w;       w += sizeof(int) * N_NODES;
    float*    dinv    = (float*)w;     w += sizeof(float) * N_NODES;
    int*      csrc    = (int*)w;       w += sizeof(int) * E_EDGES;
    unsigned* staged  = (unsigned*)w;  w += sizeof(unsigned) * (size_t)NBUCK * BUCKET_CAP;
    unsigned* HS1     = (unsigned*)w;  w += sizeof(unsigned) * (size_t)N_NODES * 32;  // 2 chunks x N x 16
    unsigned* HS2     = (unsigned*)w;  w += sizeof(unsigned) * (size_t)N_NODES * 16;  // 1 chunk

    // ---- graph preprocessing (shared by both layers) ----
    cursor_init_kernel<<<(NBUCK + 255) / 256, 256, 0, stream>>>(gcursor);
    stage_kernel<<<(E_EDGES + STAGE_CHUNK - 1) / STAGE_CHUNK, STAGE_TPB, 0, stream>>>(
        srcp, dstp, gcursor, staged, E_EDGES);
    bscan_kernel<<<1, 1024, 0, stream>>>(gcursor, boff);
    bucket_csr_kernel<<<NBUCK, 256, 0, stream>>>(staged, boff, deg, dinv, rowptr, csrc, N_NODES);

    // ---- layer 1: HS1 = bf16((x@W1)*dinv) via MFMA; fm = relu(gather) per chunk ----
    linear_mfma_kernel<64><<<512, 256, 0, stream>>>(x, W1, dinv, HS1, N_NODES);
    gather_chunk_kernel<true><<<(N_NODES + 15) / 16, 256, 0, stream>>>(
        rowptr, deg, csrc, HS1, dinv, b1, fm, 64, 0, N_NODES);
    gather_chunk_kernel<true><<<(N_NODES + 15) / 16, 256, 0, stream>>>(
        rowptr, deg, csrc, HS1 + (size_t)N_NODES * 16, dinv, b1 + 32, fm, 64, 32, N_NODES);

    // ---- layer 2: HS2 = bf16((fm@W2)*dinv) via MFMA; out = gather (one chunk) ----
    linear_mfma_kernel<32><<<512, 256, 0, stream>>>(fm, W2, dinv, HS2, N_NODES);
    gather_chunk_kernel<false><<<(N_NODES + 15) / 16, 256, 0, stream>>>(
        rowptr, deg, csrc, HS2, dinv, b2, out, 32, 0, N_NODES);
}